// Round 9
// baseline (67.541 us; speedup 1.0000x reference)
//
#include <hip/hip_runtime.h>

#define NN 8192
#define DD 128
#define NC 32           // column chunks (grid.y)
#define CPC (NN / NC)   // 256 cols per chunk
#define AW 64           // anchors per wave
#define NCLS 100
#define CAPR 192        // max rows per class

typedef short bf16x8v __attribute__((ext_vector_type(8)));
typedef float f32x4  __attribute__((ext_vector_type(4)));

constexpr float SSCALE  = 3.7982825265208916f; // sqrt((1/T)*log2(e))
constexpr float LN2     = 0.6931471805599453f;
constexpr float NEG_BIG = -1.0e30f;
constexpr float M_INIT  = -3.0e38f;

__device__ __forceinline__ float ex2(float x) { return __builtin_amdgcn_exp2f(x); }

// ---------------- kernel 1: fp32 -> bf16 (RNE), pre-scaled by sqrt(SCALE2) ----------------
__global__ __launch_bounds__(256) void k_convert(const float* __restrict__ z,
                                                 unsigned short* __restrict__ zb) {
  int i = blockIdx.x * blockDim.x + threadIdx.x;
  const float4 v = reinterpret_cast<const float4*>(z)[i];
  auto cvt = [](float f) -> unsigned short {
    unsigned u = __float_as_uint(f);
    unsigned r = (u + 0x7fffu + ((u >> 16) & 1u)) >> 16;
    return (unsigned short)r;
  };
  ushort4 o;
  o.x = cvt(v.x * SSCALE); o.y = cvt(v.y * SSCALE);
  o.z = cvt(v.z * SSCALE); o.w = cvt(v.w * SSCALE);
  reinterpret_cast<ushort4*>(zb)[i] = o;
}

// ---------------- per-16-col-tile pure LSE (label-free) ----------------
template<bool HD>
__device__ __forceinline__ void tile_lse(const f32x4 (&acc)[4], int dcl,
                                         int lr, int lg, float (&m)[4], float (&s)[4]) {
  const int jl = lg * 4;
#pragma unroll
  for (int t = 0; t < 4; ++t) {
    float x0 = acc[t][0], x1 = acc[t][1], x2 = acc[t][2], x3 = acc[t][3];
    if (HD) {
      int al = t * 16 + lr - dcl;        // diagonal iff al == jl + r
      x0 = (al == jl + 0) ? NEG_BIG : x0;
      x1 = (al == jl + 1) ? NEG_BIG : x1;
      x2 = (al == jl + 2) ? NEG_BIG : x2;
      x3 = (al == jl + 3) ? NEG_BIG : x3;
    }
    float tm = fmaxf(fmaxf(x0, x1), fmaxf(x2, x3));
    float mn = fmaxf(m[t], tm);
    float e = (ex2(x0 - mn) + ex2(x1 - mn)) + (ex2(x2 - mn) + ex2(x3 - mn));
    s[t] = fmaf(s[t], ex2(m[t] - mn), e);
    m[t] = mn;
  }
}

// ---------------- kernel 2: Gram + online LSE — no LDS, no barriers ----------------
// Wave: 64 anchors (bfr PINNED in VGPRs via asm def) x 256-col chunk; A-tiles
// streamed from L2-resident zb with a depth-1 register prefetch pipeline.
__global__ __launch_bounds__(256, 2) void k_main(const unsigned short* __restrict__ zb,
                                                 float2* __restrict__ partials) {
  const int tid  = threadIdx.x;
  const int lane = tid & 63;
  const int w    = tid >> 6;
  const int lr = lane & 15, lg = lane >> 4;
  const int rowstart = (blockIdx.x * 4 + w) * AW;  // wave's first anchor
  const int cb       = blockIdx.y;
  const int cStart   = cb * CPC;

  // hoisted anchor (B) fragments: 4 t-subtiles x 4 K-steps = 64 VGPR
  bf16x8v bfr[4][4];
#pragma unroll
  for (int t = 0; t < 4; ++t) {
    const unsigned short* rp = zb + (size_t)(rowstart + t * 16 + lr) * DD + lg * 8;
#pragma unroll
    for (int ks = 0; ks < 4; ++ks)
      bfr[t][ks] = *reinterpret_cast<const bf16x8v*>(rp + ks * 32);
  }
  // ANTI-REMAT PIN: opaque asm becomes the def of each fragment; the compiler
  // cannot re-execute it, so the 64 VGPRs stay resident across the K-loop.
#pragma unroll
  for (int t = 0; t < 4; ++t)
#pragma unroll
    for (int ks = 0; ks < 4; ++ks)
      asm volatile("" : "+v"(bfr[t][ks]));

  float m[4], s[4];
#pragma unroll
  for (int t = 0; t < 4; ++t) { m[t] = M_INIT; s[t] = 0.f; }

  // prefetch tile 0
  bf16x8v ac[4], an[4];
  {
    const unsigned short* rp = zb + (size_t)(cStart + lr) * DD + lg * 8;
    ac[0] = *reinterpret_cast<const bf16x8v*>(rp);
    ac[1] = *reinterpret_cast<const bf16x8v*>(rp + 32);
    ac[2] = *reinterpret_cast<const bf16x8v*>(rp + 64);
    ac[3] = *reinterpret_cast<const bf16x8v*>(rp + 96);
  }

#pragma unroll 2
  for (int tt = 0; tt < CPC / 16; ++tt) {
    const int c0 = cStart + tt * 16;
    if (tt + 1 < CPC / 16) {       // prefetch next tile while computing this one
      const unsigned short* rp = zb + (size_t)(c0 + 16 + lr) * DD + lg * 8;
      an[0] = *reinterpret_cast<const bf16x8v*>(rp);
      an[1] = *reinterpret_cast<const bf16x8v*>(rp + 32);
      an[2] = *reinterpret_cast<const bf16x8v*>(rp + 64);
      an[3] = *reinterpret_cast<const bf16x8v*>(rp + 96);
    }

    f32x4 acc[4];
#pragma unroll
    for (int t = 0; t < 4; ++t) {
      f32x4 a = (f32x4){0.f, 0.f, 0.f, 0.f};
      a = __builtin_amdgcn_mfma_f32_16x16x32_bf16(ac[0], bfr[t][0], a, 0, 0, 0);
      a = __builtin_amdgcn_mfma_f32_16x16x32_bf16(ac[1], bfr[t][1], a, 0, 0, 0);
      a = __builtin_amdgcn_mfma_f32_16x16x32_bf16(ac[2], bfr[t][2], a, 0, 0, 0);
      a = __builtin_amdgcn_mfma_f32_16x16x32_bf16(ac[3], bfr[t][3], a, 0, 0, 0);
      acc[t] = a;
    }

    const int dcl = c0 - rowstart;
    if ((unsigned)dcl < (unsigned)AW) tile_lse<true >(acc, dcl, lr, lg, m, s);
    else                              tile_lse<false>(acc, 0,   lr, lg, m, s);

#pragma unroll
    for (int k = 0; k < 4; ++k) ac[k] = an[k];
  }

  // merge the 4 lane-groups (xor 16, 32)
#pragma unroll
  for (int off = 16; off <= 32; off <<= 1) {
#pragma unroll
    for (int t = 0; t < 4; ++t) {
      float mo = __shfl_xor(m[t], off);
      float so = __shfl_xor(s[t], off);
      float mn = fmaxf(m[t], mo);
      s[t] = s[t] * ex2(m[t] - mn) + so * ex2(mo - mn);
      m[t] = mn;
    }
  }
  if (lg == 0) {
#pragma unroll
    for (int t = 0; t < 4; ++t)
      partials[(size_t)(rowstart + t * 16 + lr) * NC + cb] = make_float2(m[t], s[t]);
  }
}

// ---------------- kernel 3: per-class merge + exact correction + loss ----------------
__global__ __launch_bounds__(256) void k_corr(const unsigned short* __restrict__ zb,
                                              const int* __restrict__ labels,
                                              const float2* __restrict__ partials,
                                              float* __restrict__ clsum) {
  const int c = blockIdx.x;
  const int tid = threadIdx.x, lane = tid & 63, w = tid >> 6;
  __shared__ int rows[CAPR];
  __shared__ float rowm[CAPR], rowss[CAPR];
  __shared__ int nsh;
  __shared__ float clpart[4];

  // wave-synchronous deterministic compaction (wave 0 only)
  if (w == 0) {
    int base = 0;
    for (int rd = 0; rd < NN / 256; ++rd) {
      int4 v = *reinterpret_cast<const int4*>(labels + rd * 256 + lane * 4);
      int labq[4] = {v.x, v.y, v.z, v.w};
#pragma unroll
      for (int q = 0; q < 4; ++q) {
        bool mt = (labq[q] == c);
        unsigned long long mask = __ballot(mt);
        if (mt) {
          int p = base + __popcll(mask & ((1ull << lane) - 1ull));
          if (p < CAPR) rows[p] = rd * 256 + lane * 4 + q;
        }
        base += __popcll(mask);
      }
    }
    if (lane == 0) nsh = base < CAPR ? base : CAPR;
  }
  __syncthreads();
  const int n = nsh;
  if (n < 2) { if (tid == 0) clsum[c] = 0.f; return; }

  // merge the NC chunk-partials for this class's rows (row-major: streaming reads)
  for (int r = tid; r < n; r += 256) {
    const float2* p = partials + (size_t)rows[r] * NC;
    float m = M_INIT, s = 0.f;
    for (int ch = 0; ch < NC; ++ch) {
      float2 q = p[ch];
      float mn = fmaxf(m, q.x);
      s = s * ex2(m - mn) + q.y * ex2(q.x - mn);
      m = mn;
    }
    rowm[r] = m; rowss[r] = s;
  }
  __syncthreads();

  const int lr = lane & 15, lg = lane >> 4;
  const int NB = (n + 15) >> 4;
  float wloss = 0.f;
  for (int ab = w; ab < NB; ab += 4) {
    int a = ab * 16 + lr;
    bool aok = a < n;
    int ga = rows[aok ? a : 0];
    bf16x8v bf[4];
#pragma unroll
    for (int ks = 0; ks < 4; ++ks)
      bf[ks] = *reinterpret_cast<const bf16x8v*>(zb + (size_t)ga * DD + ks * 32 + lg * 8);
    float ma = aok ? rowm[a] : 0.f;
    float sumv = 0.f, sume = 0.f;
    for (int bb = 0; bb < NB; ++bb) {
      int bi = bb * 16 + lr;
      int gb = rows[bi < n ? bi : 0];
      bf16x8v af[4];
#pragma unroll
      for (int ks = 0; ks < 4; ++ks)
        af[ks] = *reinterpret_cast<const bf16x8v*>(zb + (size_t)gb * DD + ks * 32 + lg * 8);
      f32x4 acc = (f32x4){0.f, 0.f, 0.f, 0.f};
      acc = __builtin_amdgcn_mfma_f32_16x16x32_bf16(af[0], bf[0], acc, 0, 0, 0);
      acc = __builtin_amdgcn_mfma_f32_16x16x32_bf16(af[1], bf[1], acc, 0, 0, 0);
      acc = __builtin_amdgcn_mfma_f32_16x16x32_bf16(af[2], bf[2], acc, 0, 0, 0);
      acc = __builtin_amdgcn_mfma_f32_16x16x32_bf16(af[3], bf[3], acc, 0, 0, 0);
#pragma unroll
      for (int r = 0; r < 4; ++r) {
        int b = bb * 16 + lg * 4 + r;
        bool ok = (b < n) && (b != a);
        float v = acc[r];
        sumv += ok ? v : 0.f;
        float e = ex2(v - ma);
        sume += ok ? e : 0.f;
      }
    }
#pragma unroll
    for (int off = 16; off <= 32; off <<= 1) {
      sumv += __shfl_xor(sumv, off);
      sume += __shfl_xor(sume, off);
    }
    if (lg == 0 && aok) {
      float sp = rowss[a] - 0.5f * sume;           // apply 0.5 weight to matches
      wloss += LN2 * (ma + log2f(sp)) - LN2 * sumv / (float)(n - 1);
    }
  }
#pragma unroll
  for (int off = 32; off >= 1; off >>= 1) wloss += __shfl_xor(wloss, off);
  if (lane == 0) clpart[w] = wloss;
  __syncthreads();
  if (tid == 0) clsum[c] = (clpart[0] + clpart[1]) + (clpart[2] + clpart[3]);
}

// ---------------- kernel 4: final sum over classes ----------------
__global__ __launch_bounds__(128) void k_final(const float* __restrict__ clsum,
                                               float* __restrict__ out) {
  const int tid = threadIdx.x;
  float v = (tid < NCLS) ? clsum[tid] : 0.f;
#pragma unroll
  for (int off = 32; off >= 1; off >>= 1) v += __shfl_xor(v, off);
  __shared__ float t2[2];
  if ((tid & 63) == 0) t2[tid >> 6] = v;
  __syncthreads();
  if (tid == 0) out[0] = (t2[0] + t2[1]) * (1.0f / (float)NN);
}

extern "C" void kernel_launch(void* const* d_in, const int* in_sizes, int n_in,
                              void* d_out, int out_size, void* d_ws, size_t ws_size,
                              hipStream_t stream) {
  const float* z      = (const float*)d_in[0];
  const int*   labels = (const int*)d_in[1];

  char* ws = (char*)d_ws;
  unsigned short* zb = (unsigned short*)ws;                                 // 2 MB
  float2* partials   = (float2*)(ws + (size_t)NN * DD * 2);                 // NN*NC*8 = 2 MB
  float*  clsum      = (float*)(ws + (size_t)NN * DD * 2 + (size_t)NN * NC * 8);

  hipLaunchKernelGGL(k_convert, dim3(NN * DD / 4 / 256), dim3(256), 0, stream, z, zb);
  hipLaunchKernelGGL(k_main,    dim3(NN / (4 * AW), NC), dim3(256), 0, stream, zb, partials);
  hipLaunchKernelGGL(k_corr,    dim3(NCLS), dim3(256), 0, stream, zb, labels, partials, clsum);
  hipLaunchKernelGGL(k_final,   dim3(1), dim3(128), 0, stream, clsum, (float*)d_out);
}

// Round 10
// 60.379 us; speedup vs baseline: 1.1186x; 1.1186x over previous
//
#include <hip/hip_runtime.h>

#define NN 8192
#define DD 128
#define NC 32           // column chunks (grid.y)
#define CPC (NN / NC)   // 256 cols per chunk
#define AW 64           // anchors per wave
#define NCLS 100
#define CAPR 192        // max rows per class

typedef short bf16x8v __attribute__((ext_vector_type(8)));
typedef float f32x4  __attribute__((ext_vector_type(4)));

constexpr float SSCALE  = 3.7982825265208916f; // sqrt((1/T)*log2(e))
constexpr float LN2     = 0.6931471805599453f;
constexpr float NEG_BIG = -1.0e30f;
constexpr float M_INIT  = -3.0e38f;

__device__ __forceinline__ float ex2(float x) { return __builtin_amdgcn_exp2f(x); }

// ---------------- kernel 1: fp32 -> bf16 (RNE), pre-scaled by sqrt(SCALE2) ----------------
__global__ __launch_bounds__(256) void k_convert(const float* __restrict__ z,
                                                 unsigned short* __restrict__ zb) {
  int i = blockIdx.x * blockDim.x + threadIdx.x;
  const float4 v = reinterpret_cast<const float4*>(z)[i];
  auto cvt = [](float f) -> unsigned short {
    unsigned u = __float_as_uint(f);
    unsigned r = (u + 0x7fffu + ((u >> 16) & 1u)) >> 16;
    return (unsigned short)r;
  };
  ushort4 o;
  o.x = cvt(v.x * SSCALE); o.y = cvt(v.y * SSCALE);
  o.z = cvt(v.z * SSCALE); o.w = cvt(v.w * SSCALE);
  reinterpret_cast<ushort4*>(zb)[i] = o;
}

// ---------------- per-16-col-tile pure LSE (label-free) ----------------
template<bool HD>
__device__ __forceinline__ void tile_lse(const f32x4 (&acc)[4], int dcl,
                                         int lr, int lg, float (&m)[4], float (&s)[4]) {
  const int jl = lg * 4;
#pragma unroll
  for (int t = 0; t < 4; ++t) {
    float x0 = acc[t][0], x1 = acc[t][1], x2 = acc[t][2], x3 = acc[t][3];
    if (HD) {
      int al = t * 16 + lr - dcl;        // diagonal iff al == jl + r
      x0 = (al == jl + 0) ? NEG_BIG : x0;
      x1 = (al == jl + 1) ? NEG_BIG : x1;
      x2 = (al == jl + 2) ? NEG_BIG : x2;
      x3 = (al == jl + 3) ? NEG_BIG : x3;
    }
    float tm = fmaxf(fmaxf(x0, x1), fmaxf(x2, x3));
    float mn = fmaxf(m[t], tm);
    float e = (ex2(x0 - mn) + ex2(x1 - mn)) + (ex2(x2 - mn) + ex2(x3 - mn));
    s[t] = fmaf(s[t], ex2(m[t] - mn), e);
    m[t] = mn;
  }
}

// ---------------- kernel 2: Gram + online LSE — no LDS, no barriers ----------------
// Wave: 64 anchors (bfr resident, pinned def) x 256-col chunk; A-tiles streamed
// from L2-resident zb with a depth-1 register prefetch pipeline.
// launch_bounds(256,3): 170-reg budget -> 3 waves/SIMD residency (the R8/R9
// (256,2) setting let the allocator eat 256 regs and starved TLP at 2 waves).
__global__ __launch_bounds__(256, 3) void k_main(const unsigned short* __restrict__ zb,
                                                 float2* __restrict__ partials) {
  const int tid  = threadIdx.x;
  const int lane = tid & 63;
  const int w    = tid >> 6;
  const int lr = lane & 15, lg = lane >> 4;
  const int rowstart = (blockIdx.x * 4 + w) * AW;  // wave's first anchor
  const int cb       = blockIdx.y;
  const int cStart   = cb * CPC;

  // hoisted anchor (B) fragments: 4 t-subtiles x 4 K-steps = 64 regs
  bf16x8v bfr[4][4];
#pragma unroll
  for (int t = 0; t < 4; ++t) {
    const unsigned short* rp = zb + (size_t)(rowstart + t * 16 + lr) * DD + lg * 8;
#pragma unroll
    for (int ks = 0; ks < 4; ++ks)
      bfr[t][ks] = *reinterpret_cast<const bf16x8v*>(rp + ks * 32);
  }
  // ANTI-REMAT PIN: opaque asm is the def; compiler must keep values resident
  // (VGPR or AGPR — MFMA reads either on gfx950).
#pragma unroll
  for (int t = 0; t < 4; ++t)
#pragma unroll
    for (int ks = 0; ks < 4; ++ks)
      asm volatile("" : "+v"(bfr[t][ks]));

  float m[4], s[4];
#pragma unroll
  for (int t = 0; t < 4; ++t) { m[t] = M_INIT; s[t] = 0.f; }

  // prefetch tile 0
  bf16x8v ac[4], an[4];
  {
    const unsigned short* rp = zb + (size_t)(cStart + lr) * DD + lg * 8;
    ac[0] = *reinterpret_cast<const bf16x8v*>(rp);
    ac[1] = *reinterpret_cast<const bf16x8v*>(rp + 32);
    ac[2] = *reinterpret_cast<const bf16x8v*>(rp + 64);
    ac[3] = *reinterpret_cast<const bf16x8v*>(rp + 96);
  }

#pragma unroll 2
  for (int tt = 0; tt < CPC / 16; ++tt) {
    const int c0 = cStart + tt * 16;
    if (tt + 1 < CPC / 16) {       // prefetch next tile while computing this one
      const unsigned short* rp = zb + (size_t)(c0 + 16 + lr) * DD + lg * 8;
      an[0] = *reinterpret_cast<const bf16x8v*>(rp);
      an[1] = *reinterpret_cast<const bf16x8v*>(rp + 32);
      an[2] = *reinterpret_cast<const bf16x8v*>(rp + 64);
      an[3] = *reinterpret_cast<const bf16x8v*>(rp + 96);
    }

    f32x4 acc[4];
#pragma unroll
    for (int t = 0; t < 4; ++t) {
      f32x4 a = (f32x4){0.f, 0.f, 0.f, 0.f};
      a = __builtin_amdgcn_mfma_f32_16x16x32_bf16(ac[0], bfr[t][0], a, 0, 0, 0);
      a = __builtin_amdgcn_mfma_f32_16x16x32_bf16(ac[1], bfr[t][1], a, 0, 0, 0);
      a = __builtin_amdgcn_mfma_f32_16x16x32_bf16(ac[2], bfr[t][2], a, 0, 0, 0);
      a = __builtin_amdgcn_mfma_f32_16x16x32_bf16(ac[3], bfr[t][3], a, 0, 0, 0);
      acc[t] = a;
    }

    const int dcl = c0 - rowstart;
    if ((unsigned)dcl < (unsigned)AW) tile_lse<true >(acc, dcl, lr, lg, m, s);
    else                              tile_lse<false>(acc, 0,   lr, lg, m, s);

#pragma unroll
    for (int k = 0; k < 4; ++k) ac[k] = an[k];
  }

  // merge the 4 lane-groups (xor 16, 32)
#pragma unroll
  for (int off = 16; off <= 32; off <<= 1) {
#pragma unroll
    for (int t = 0; t < 4; ++t) {
      float mo = __shfl_xor(m[t], off);
      float so = __shfl_xor(s[t], off);
      float mn = fmaxf(m[t], mo);
      s[t] = s[t] * ex2(m[t] - mn) + so * ex2(mo - mn);
      m[t] = mn;
    }
  }
  if (lg == 0) {
#pragma unroll
    for (int t = 0; t < 4; ++t)
      partials[(size_t)(rowstart + t * 16 + lr) * NC + cb] = make_float2(m[t], s[t]);
  }
}

// ---------------- kernel 3: per-class merge + exact correction + loss ----------------
__global__ __launch_bounds__(256) void k_corr(const unsigned short* __restrict__ zb,
                                              const int* __restrict__ labels,
                                              const float2* __restrict__ partials,
                                              float* __restrict__ clsum) {
  const int c = blockIdx.x;
  const int tid = threadIdx.x, lane = tid & 63, w = tid >> 6;
  __shared__ int rows[CAPR];
  __shared__ float rowm[CAPR], rowss[CAPR];
  __shared__ int wavecnt[4];
  __shared__ float clpart[4];

  // 4-wave striped compaction, two-pass (stripe-major order, deterministic).
  // Wave w owns labels [w*2048, (w+1)*2048).
  int mycnt = 0;
  {
    const int base = w * (NN / 4);
    for (int rd = 0; rd < (NN / 4) / 256; ++rd) {        // 8 rounds
      int4 v = *reinterpret_cast<const int4*>(labels + base + rd * 256 + lane * 4);
#pragma unroll
      for (int q = 0; q < 4; ++q) {
        int lq = (q == 0) ? v.x : (q == 1) ? v.y : (q == 2) ? v.z : v.w;
        mycnt += __popcll(__ballot(lq == c));
      }
    }
    mycnt = __popcll(__ballot(false)) + mycnt;           // no-op keep wave-sync
    if (lane == 0) wavecnt[w] = mycnt;
  }
  __syncthreads();
  int off0 = 0, total = 0;
#pragma unroll
  for (int ww = 0; ww < 4; ++ww) {
    if (ww < w) off0 += wavecnt[ww];
    total += wavecnt[ww];
  }
  {
    const int base = w * (NN / 4);
    int pos = off0;
    for (int rd = 0; rd < (NN / 4) / 256; ++rd) {        // 8 rounds (L1-hot)
      int4 v = *reinterpret_cast<const int4*>(labels + base + rd * 256 + lane * 4);
#pragma unroll
      for (int q = 0; q < 4; ++q) {
        int lq = (q == 0) ? v.x : (q == 1) ? v.y : (q == 2) ? v.z : v.w;
        bool mt = (lq == c);
        unsigned long long mask = __ballot(mt);
        if (mt) {
          int p = pos + __popcll(mask & ((1ull << lane) - 1ull));
          if (p < CAPR) rows[p] = base + rd * 256 + lane * 4 + q;
        }
        pos += __popcll(mask);
      }
    }
  }
  __syncthreads();
  const int n = total < CAPR ? total : CAPR;
  if (n < 2) { if (tid == 0) clsum[c] = 0.f; return; }

  // merge the NC chunk-partials per row (unrolled: 32 independent loads -> MLP)
  for (int r = tid; r < n; r += 256) {
    const float2* p = partials + (size_t)rows[r] * NC;
    float m = M_INIT, s = 0.f;
#pragma unroll
    for (int ch = 0; ch < NC; ++ch) {
      float2 q = p[ch];
      float mn = fmaxf(m, q.x);
      s = s * ex2(m - mn) + q.y * ex2(q.x - mn);
      m = mn;
    }
    rowm[r] = m; rowss[r] = s;
  }
  __syncthreads();

  const int lr = lane & 15, lg = lane >> 4;
  const int NB = (n + 15) >> 4;
  float wloss = 0.f;
  for (int ab = w; ab < NB; ab += 4) {
    int a = ab * 16 + lr;
    bool aok = a < n;
    int ga = rows[aok ? a : 0];
    bf16x8v bf[4];
#pragma unroll
    for (int ks = 0; ks < 4; ++ks)
      bf[ks] = *reinterpret_cast<const bf16x8v*>(zb + (size_t)ga * DD + ks * 32 + lg * 8);
    float ma = aok ? rowm[a] : 0.f;
    float sumv = 0.f, sume = 0.f;
    for (int bb = 0; bb < NB; ++bb) {
      int bi = bb * 16 + lr;
      int gb = rows[bi < n ? bi : 0];
      bf16x8v af[4];
#pragma unroll
      for (int ks = 0; ks < 4; ++ks)
        af[ks] = *reinterpret_cast<const bf16x8v*>(zb + (size_t)gb * DD + ks * 32 + lg * 8);
      f32x4 acc = (f32x4){0.f, 0.f, 0.f, 0.f};
      acc = __builtin_amdgcn_mfma_f32_16x16x32_bf16(af[0], bf[0], acc, 0, 0, 0);
      acc = __builtin_amdgcn_mfma_f32_16x16x32_bf16(af[1], bf[1], acc, 0, 0, 0);
      acc = __builtin_amdgcn_mfma_f32_16x16x32_bf16(af[2], bf[2], acc, 0, 0, 0);
      acc = __builtin_amdgcn_mfma_f32_16x16x32_bf16(af[3], bf[3], acc, 0, 0, 0);
#pragma unroll
      for (int r = 0; r < 4; ++r) {
        int b = bb * 16 + lg * 4 + r;
        bool ok = (b < n) && (b != a);
        float v = acc[r];
        sumv += ok ? v : 0.f;
        float e = ex2(v - ma);
        sume += ok ? e : 0.f;
      }
    }
#pragma unroll
    for (int off = 16; off <= 32; off <<= 1) {
      sumv += __shfl_xor(sumv, off);
      sume += __shfl_xor(sume, off);
    }
    if (lg == 0 && aok) {
      float sp = rowss[a] - 0.5f * sume;           // apply 0.5 weight to matches
      wloss += LN2 * (ma + log2f(sp)) - LN2 * sumv / (float)(n - 1);
    }
  }
#pragma unroll
  for (int off = 32; off >= 1; off >>= 1) wloss += __shfl_xor(wloss, off);
  if (lane == 0) clpart[w] = wloss;
  __syncthreads();
  if (tid == 0) clsum[c] = (clpart[0] + clpart[1]) + (clpart[2] + clpart[3]);
}

// ---------------- kernel 4: final sum over classes ----------------
__global__ __launch_bounds__(128) void k_final(const float* __restrict__ clsum,
                                               float* __restrict__ out) {
  const int tid = threadIdx.x;
  float v = (tid < NCLS) ? clsum[tid] : 0.f;
#pragma unroll
  for (int off = 32; off >= 1; off >>= 1) v += __shfl_xor(v, off);
  __shared__ float t2[2];
  if ((tid & 63) == 0) t2[tid >> 6] = v;
  __syncthreads();
  if (tid == 0) out[0] = (t2[0] + t2[1]) * (1.0f / (float)NN);
}

extern "C" void kernel_launch(void* const* d_in, const int* in_sizes, int n_in,
                              void* d_out, int out_size, void* d_ws, size_t ws_size,
                              hipStream_t stream) {
  const float* z      = (const float*)d_in[0];
  const int*   labels = (const int*)d_in[1];

  char* ws = (char*)d_ws;
  unsigned short* zb = (unsigned short*)ws;                                 // 2 MB
  float2* partials   = (float2*)(ws + (size_t)NN * DD * 2);                 // NN*NC*8 = 2 MB
  float*  clsum      = (float*)(ws + (size_t)NN * DD * 2 + (size_t)NN * NC * 8);

  hipLaunchKernelGGL(k_convert, dim3(NN * DD / 4 / 256), dim3(256), 0, stream, z, zb);
  hipLaunchKernelGGL(k_main,    dim3(NN / (4 * AW), NC), dim3(256), 0, stream, zb, partials);
  hipLaunchKernelGGL(k_corr,    dim3(NCLS), dim3(256), 0, stream, zb, labels, partials, clsum);
  hipLaunchKernelGGL(k_final,   dim3(1), dim3(128), 0, stream, clsum, (float*)d_out);
}